// Round 1
// baseline (210.966 us; speedup 1.0000x reference)
//
#include <hip/hip_runtime.h>

#define N_NODES 4096
#define B_PTS   4096
#define SUPPORT_FACTOR 2.5f
#define EPSILON 1e-5f

// ---------------------------------------------------------------------------
// Kernel 1: per-node nearest-neighbor distance (unchanged, ~4 us).
// ---------------------------------------------------------------------------
__global__ __launch_bounds__(256) void nearest_kernel(
        const float* __restrict__ nodes, float* __restrict__ mind) {
    const int i = blockIdx.x;
    const float xi = nodes[2 * i];
    const float yi = nodes[2 * i + 1];

    const float4* nodes4 = (const float4*)nodes;  // 2 nodes per float4
    float mind2 = 3.4e38f;
    for (int k = threadIdx.x; k < N_NODES / 2; k += 256) {
        float4 v = nodes4[k];
        float dx0 = xi - v.x, dy0 = yi - v.y;
        float dx1 = xi - v.z, dy1 = yi - v.w;
        float d20 = dx0 * dx0 + dy0 * dy0;
        float d21 = dx1 * dx1 + dy1 * dy1;
        if (2 * k != i)     mind2 = fminf(mind2, d20);
        if (2 * k + 1 != i) mind2 = fminf(mind2, d21);
    }
    #pragma unroll
    for (int off = 32; off > 0; off >>= 1)
        mind2 = fminf(mind2, __shfl_down(mind2, off, 64));

    __shared__ float sw[4];
    const int wave = threadIdx.x >> 6;
    if ((threadIdx.x & 63) == 0) sw[wave] = mind2;
    __syncthreads();
    if (threadIdx.x == 0) {
        float m = fminf(fminf(sw[0], sw[1]), fminf(sw[2], sw[3]));
        mind[i] = sqrtf(m);
    }
}

// ---------------------------------------------------------------------------
// Kernel 2: single-block dilation reduce. Consumes mind[0..4095], then
// overwrites mind[0]=1/dilation, mind[1]=conservative r^2 cutoff.
// (write happens after the barrier, all reads already consumed -> no race;
//  keeps workspace footprint at the same 16 KB as before)
// ---------------------------------------------------------------------------
__global__ __launch_bounds__(256) void dil_kernel(float* __restrict__ mind) {
    __shared__ float sw[4];
    const int tid = threadIdx.x;
    const float4* m4 = (const float4*)mind;
    float s = 0.f;
    #pragma unroll
    for (int k = 0; k < 4; ++k) {
        float4 v = m4[k * 256 + tid];
        s += (v.x + v.y) + (v.z + v.w);
    }
    #pragma unroll
    for (int off = 32; off > 0; off >>= 1)
        s += __shfl_down(s, off, 64);
    if ((tid & 63) == 0) sw[tid >> 6] = s;
    __syncthreads();
    if (tid == 0) {
        float dil = (sw[0] + sw[1] + sw[2] + sw[3]) *
                    (SUPPORT_FACTOR / (float)N_NODES);
        mind[0] = 1.0f / dil;                    // inv_dil
        // margin 2e-4 relative >> sqrt/div rounding: never skips a w!=0 node
        mind[1] = dil * dil * 1.0002f + 1e-9f;   // r^2 cutoff for early-out
    }
}

// ---------------------------------------------------------------------------
// Cubic spline weight (zero outside q > 1)
// ---------------------------------------------------------------------------
__device__ __forceinline__ float cubic_w(float q) {
    if (q <= 0.5f) return 2.0f / 3.0f + q * q * (4.0f * q - 4.0f);
    if (q <= 1.0f) return 4.0f / 3.0f + q * (-4.0f + q * (4.0f - (4.0f / 3.0f) * q));
    return 0.0f;
}

// ---------------------------------------------------------------------------
// Kernel 3 (sparse): one block per query point b.
//  Entry:   issue 12 float4 zero-stores covering this block's 3 output rows
//           (48 KB) -> they drain at memset BW while phase 1 computes.
//  Phase 1: moment matrix over all nodes, 4-node-group early-out on
//           min(d^2) > r2m (skipped groups contribute exactly 0 to M).
//  Phase 2: tid 0 analytic adjugate inverse (negated deriv rows).
//  Phase 3: scatter ONLY w != 0 entries (~20 nodes/query x 3 floats).
//           The __syncthreads barriers (vmcnt(0) drain) order the zero
//           stores before the scatter stores within the block; each block
//           owns its rows exclusively, so no cross-block hazard.
// ---------------------------------------------------------------------------
__global__ __launch_bounds__(256) void rkpm_sparse(
        const float* __restrict__ x, const float* __restrict__ nodes,
        const float* __restrict__ dilp, float* __restrict__ out) {
    __shared__ float sred[4][6];
    __shared__ float sbc[9];   // inverse rows (phi, -dx, -dy)

    const int b = blockIdx.x;
    const int tid = threadIdx.x;
    const int wave = tid >> 6;
    const int lane = tid & 63;

    const size_t BN = (size_t)B_PTS * N_NODES;
    float* __restrict__ row0 = out + (size_t)b * N_NODES;        // phi
    float* __restrict__ row1 = row0 + BN;                        // phi_x
    float* __restrict__ row2 = row1 + BN;                        // phi_y

    // ---- zero own rows first; stores overlap phase-1 compute ----
    {
        float4 z4; z4.x = 0.f; z4.y = 0.f; z4.z = 0.f; z4.w = 0.f;
        float4* p0 = (float4*)row0;
        float4* p1 = (float4*)row1;
        float4* p2 = (float4*)row2;
        #pragma unroll
        for (int k = 0; k < 4; ++k) {
            p0[k * 256 + tid] = z4;
            p1[k * 256 + tid] = z4;
            p2[k * 256 + tid] = z4;
        }
    }

    const float inv_dil = dilp[0];
    const float r2m     = dilp[1];
    const float2 xq = ((const float2*)x)[b];
    const float xb = xq.x, yb = xq.y;

    // ---- phase 1: moment matrix with early-out ----
    const float4* nodes4 = (const float4*)nodes;   // 2 nodes per float4
    float m00 = 0.f, m01 = 0.f, m02 = 0.f, m11 = 0.f, m12 = 0.f, m22 = 0.f;
    #pragma unroll
    for (int kk = 0; kk < 4; ++kk) {
        float4 va = nodes4[kk * 512 + 2 * tid];      // nodes j, j+1
        float4 vb = nodes4[kk * 512 + 2 * tid + 1];  // nodes j+2, j+3
        float dx0 = xb - va.x, dy0 = yb - va.y;
        float dx1 = xb - va.z, dy1 = yb - va.w;
        float dx2 = xb - vb.x, dy2 = yb - vb.y;
        float dx3 = xb - vb.z, dy3 = yb - vb.w;
        float d0 = dx0 * dx0 + dy0 * dy0;
        float d1 = dx1 * dx1 + dy1 * dy1;
        float d2 = dx2 * dx2 + dy2 * dy2;
        float d3 = dx3 * dx3 + dy3 * dy3;
        float dmin = fminf(fminf(d0, d1), fminf(d2, d3));
        if (dmin <= r2m) {
            float w0 = cubic_w(sqrtf(d0 + 1e-10f) * inv_dil);
            float w1 = cubic_w(sqrtf(d1 + 1e-10f) * inv_dil);
            float w2 = cubic_w(sqrtf(d2 + 1e-10f) * inv_dil);
            float w3 = cubic_w(sqrtf(d3 + 1e-10f) * inv_dil);
            m00 += (w0 + w1) + (w2 + w3);
            m01 += (w0 * dx0 + w1 * dx1) + (w2 * dx2 + w3 * dx3);
            m02 += (w0 * dy0 + w1 * dy1) + (w2 * dy2 + w3 * dy3);
            m11 += (w0 * dx0 * dx0 + w1 * dx1 * dx1) + (w2 * dx2 * dx2 + w3 * dx3 * dx3);
            m12 += (w0 * dx0 * dy0 + w1 * dx1 * dy1) + (w2 * dx2 * dy2 + w3 * dx3 * dy3);
            m22 += (w0 * dy0 * dy0 + w1 * dy1 * dy1) + (w2 * dy2 * dy2 + w3 * dy3 * dy3);
        }
    }
    #pragma unroll
    for (int off = 32; off > 0; off >>= 1) {
        m00 += __shfl_down(m00, off, 64);
        m01 += __shfl_down(m01, off, 64);
        m02 += __shfl_down(m02, off, 64);
        m11 += __shfl_down(m11, off, 64);
        m12 += __shfl_down(m12, off, 64);
        m22 += __shfl_down(m22, off, 64);
    }
    if (lane == 0) {
        sred[wave][0] = m00; sred[wave][1] = m01; sred[wave][2] = m02;
        sred[wave][3] = m11; sred[wave][4] = m12; sred[wave][5] = m22;
    }
    __syncthreads();   // also drains the zero-stores (vmcnt(0) before barrier)

    // ---- phase 2: analytic symmetric 3x3 inverse ----
    if (tid == 0) {
        float a  = sred[0][0] + sred[1][0] + sred[2][0] + sred[3][0] + EPSILON;
        float bb = sred[0][1] + sred[1][1] + sred[2][1] + sred[3][1];
        float c  = sred[0][2] + sred[1][2] + sred[2][2] + sred[3][2];
        float d  = sred[0][3] + sred[1][3] + sred[2][3] + sred[3][3] + EPSILON;
        float e  = sred[0][4] + sred[1][4] + sred[2][4] + sred[3][4];
        float f  = sred[0][5] + sred[1][5] + sred[2][5] + sred[3][5] + EPSILON;
        float c00 = d * f - e * e;
        float c01 = c * e - bb * f;
        float c02 = bb * e - c * d;
        float det = a * c00 + bb * c01 + c * c02;
        float idet = 1.0f / det;
        float i00 = c00 * idet;
        float i01 = c01 * idet;
        float i02 = c02 * idet;
        float i11 = (a * f - c * c) * idet;
        float i12 = (bb * c - a * e) * idet;
        float i22 = (a * d - bb * bb) * idet;
        sbc[0] = i00;  sbc[1] = i01;  sbc[2] = i02;   // phi row
        sbc[3] = -i01; sbc[4] = -i11; sbc[5] = -i12;  // phi_x row (negated)
        sbc[6] = -i02; sbc[7] = -i12; sbc[8] = -i22;  // phi_y row (negated)
    }
    __syncthreads();

    const float i00 = sbc[0], i01 = sbc[1], i02  = sbc[2];
    const float n01 = sbc[3], n11 = sbc[4], n12  = sbc[5];
    const float n02 = sbc[6], n12b = sbc[7], n22 = sbc[8];

    // ---- phase 3: scatter only nonzero entries ----
    #define SCATTER(DX, DY, DD, J)                                          \
        {                                                                   \
            float w_ = cubic_w(sqrtf((DD) + 1e-10f) * inv_dil);             \
            if (w_ != 0.0f) {                                               \
                row0[J] = w_ * (i00 + i01 * (DX) + i02  * (DY));            \
                row1[J] = w_ * (n01 + n11 * (DX) + n12  * (DY));            \
                row2[J] = w_ * (n02 + n12b * (DX) + n22 * (DY));            \
            }                                                               \
        }

    #pragma unroll
    for (int kk = 0; kk < 4; ++kk) {
        float4 va = nodes4[kk * 512 + 2 * tid];
        float4 vb = nodes4[kk * 512 + 2 * tid + 1];
        float dx0 = xb - va.x, dy0 = yb - va.y;
        float dx1 = xb - va.z, dy1 = yb - va.w;
        float dx2 = xb - vb.x, dy2 = yb - vb.y;
        float dx3 = xb - vb.z, dy3 = yb - vb.w;
        float d0 = dx0 * dx0 + dy0 * dy0;
        float d1 = dx1 * dx1 + dy1 * dy1;
        float d2 = dx2 * dx2 + dy2 * dy2;
        float d3 = dx3 * dx3 + dy3 * dy3;
        float dmin = fminf(fminf(d0, d1), fminf(d2, d3));
        if (dmin <= r2m) {
            const int j = kk * 1024 + 4 * tid;
            SCATTER(dx0, dy0, d0, j);
            SCATTER(dx1, dy1, d1, j + 1);
            SCATTER(dx2, dy2, d2, j + 2);
            SCATTER(dx3, dy3, d3, j + 3);
        }
    }
    #undef SCATTER
}

extern "C" void kernel_launch(void* const* d_in, const int* in_sizes, int n_in,
                              void* d_out, int out_size, void* d_ws, size_t ws_size,
                              hipStream_t stream) {
    const float* x     = (const float*)d_in[0];   // [4096, 2]
    const float* nodes = (const float*)d_in[1];   // [4096, 2]
    float* out  = (float*)d_out;                  // 3 * 4096 * 4096 floats
    float* mind = (float*)d_ws;                   // [4096] nearest distances

    nearest_kernel<<<N_NODES, 256, 0, stream>>>(nodes, mind);
    dil_kernel<<<1, 256, 0, stream>>>(mind);
    rkpm_sparse<<<B_PTS, 256, 0, stream>>>(x, nodes, mind, out);
}